// Round 1
// baseline (183.511 us; speedup 1.0000x reference)
//
#include <hip/hip_runtime.h>
#include <hip/hip_bf16.h>

typedef float f32x4 __attribute__((ext_vector_type(4)));
typedef __bf16 bf16x8 __attribute__((ext_vector_type(8)));

#define D_DIM 128

// fp32 -> bf16 round-to-nearest-even (no NaN handling needed here)
static __device__ inline unsigned short f2bf(float f) {
    unsigned u = __float_as_uint(f);
    u += 0x7fffu + ((u >> 16) & 1u);
    return (unsigned short)(u >> 16);
}

__global__ void zero_kernel(float* __restrict__ p, int n) {
    int i = blockIdx.x * 256 + threadIdx.x;
    if (i < n) p[i] = 0.0f;
}

// One wave per row: L2-normalize and store bf16.
__global__ __launch_bounds__(256) void norm_kernel(const float* __restrict__ X,
                                                   unsigned short* __restrict__ E) {
    int row  = blockIdx.x * 4 + (threadIdx.x >> 6);
    int lane = threadIdx.x & 63;
    const float2 v = *reinterpret_cast<const float2*>(X + (size_t)row * D_DIM + lane * 2);
    float ss = v.x * v.x + v.y * v.y;
    #pragma unroll
    for (int m = 32; m; m >>= 1) ss += __shfl_xor(ss, m);
    float rn = rsqrtf(ss);
    ushort2 o;
    o.x = f2bf(v.x * rn);
    o.y = f2bf(v.y * rn);
    *reinterpret_cast<ushort2*>(E + (size_t)row * D_DIM + lane * 2) = o;
}

// Fused sim + exp-sum + masked-sim-sum.
// Block = 4 waves; wave w owns rows m0 = blockIdx.x*64 + w*16 .. +16.
// blockIdx.y = j-split (each covers jlen columns).
__global__ __launch_bounds__(256) void main_kernel(const unsigned short* __restrict__ E,
                                                   const int* __restrict__ labels,
                                                   float* __restrict__ S1,
                                                   float* __restrict__ S2,
                                                   int N, int jlen) {
    int tid  = threadIdx.x;
    int wave = tid >> 6;
    int lane = tid & 63;
    int l15  = lane & 15;
    int lhi  = lane >> 4;

    int m0 = blockIdx.x * 64 + wave * 16;
    int j0 = blockIdx.y * jlen;

    // A fragments: row m0 + l15, k = kb*32 + lhi*8 (+0..7)
    const unsigned short* arow = E + (size_t)(m0 + l15) * D_DIM + lhi * 8;
    bf16x8 afrag[4];
    #pragma unroll
    for (int kb = 0; kb < 4; kb++)
        afrag[kb] = *reinterpret_cast<const bf16x8*>(arow + kb * 32);

    // Epilogue row labels: rows m0 + lhi*4 + r
    int rlab[4];
    #pragma unroll
    for (int r = 0; r < 4; r++) rlab[r] = labels[m0 + lhi * 4 + r];

    float s1[4] = {0.f, 0.f, 0.f, 0.f};
    float s2[4] = {0.f, 0.f, 0.f, 0.f};

    for (int jt = j0; jt < j0 + jlen; jt += 16) {
        int c = jt + l15;
        const unsigned short* brow = E + (size_t)c * D_DIM + lhi * 8;
        f32x4 acc = {0.f, 0.f, 0.f, 0.f};
        #pragma unroll
        for (int kb = 0; kb < 4; kb++) {
            bf16x8 bfrag = *reinterpret_cast<const bf16x8*>(brow + kb * 32);
            acc = __builtin_amdgcn_mfma_f32_16x16x32_bf16(afrag[kb], bfrag, acc, 0, 0, 0);
        }
        int clab = labels[c];
        #pragma unroll
        for (int r = 0; r < 4; r++) {
            float sim = acc[r];               // row = m0+lhi*4+r, col = jt+l15
            s1[r] += __expf(sim);
            s2[r] += (clab == rlab[r]) ? sim : 0.0f;
        }
    }

    // Reduce across the 16 lanes of each row-group (xor masks stay in-group).
    #pragma unroll
    for (int m = 1; m < 16; m <<= 1) {
        #pragma unroll
        for (int r = 0; r < 4; r++) {
            s1[r] += __shfl_xor(s1[r], m);
            s2[r] += __shfl_xor(s2[r], m);
        }
    }
    if (l15 == 0) {
        #pragma unroll
        for (int r = 0; r < 4; r++) {
            atomicAdd(&S1[m0 + lhi * 4 + r], s1[r]);
            atomicAdd(&S2[m0 + lhi * 4 + r], s2[r]);
        }
    }
}

// Single block: count class0, then loss_i = cnt_i*log(S1_i - e) - (S2_i - 1),
// summed (class0 part / count0).
__global__ __launch_bounds__(1024) void finish_kernel(const float* __restrict__ S1,
                                                      const float* __restrict__ S2,
                                                      const int* __restrict__ labels,
                                                      float* __restrict__ out, int N) {
    __shared__ int    cred[16];
    __shared__ double redd[16];
    int tid = threadIdx.x;

    int c = 0;
    for (int i = tid; i < N; i += 1024) c += (labels[i] == 0);
    #pragma unroll
    for (int m = 32; m; m >>= 1) c += __shfl_xor(c, m);
    if ((tid & 63) == 0) cred[tid >> 6] = c;
    __syncthreads();
    int c0 = 0;
    #pragma unroll
    for (int w = 0; w < 16; w++) c0 += cred[w];
    float fc0 = (float)c0;
    float fc1 = (float)(N - c0);

    const float E1 = expf(1.0f);
    double local = 0.0;
    for (int i = tid; i < N; i += 1024) {
        int lab   = labels[i];
        float cnt = ((lab == 0) ? fc0 : fc1) - 1.0f;
        float denom = S1[i] - E1;
        float li  = cnt * logf(denom) - (S2[i] - 1.0f);
        local += (lab == 0) ? ((double)li / (double)fc0) : (double)li;
    }
    #pragma unroll
    for (int m = 32; m; m >>= 1) local += __shfl_xor(local, m);
    if ((tid & 63) == 0) redd[tid >> 6] = local;
    __syncthreads();
    if (tid == 0) {
        double tot = 0.0;
        #pragma unroll
        for (int w = 0; w < 16; w++) tot += redd[w];
        out[0] = (float)tot;
    }
}

extern "C" void kernel_launch(void* const* d_in, const int* in_sizes, int n_in,
                              void* d_out, int out_size, void* d_ws, size_t ws_size,
                              hipStream_t stream) {
    (void)n_in; (void)out_size; (void)ws_size;
    const float* X      = (const float*)d_in[0];
    const int*   labels = (const int*)d_in[1];
    int N = in_sizes[1];                    // 8192; kernels assume D==128, N%64==0

    unsigned short* E  = (unsigned short*)d_ws;
    float*          S1 = (float*)((char*)d_ws + (size_t)N * D_DIM * 2);
    float*          S2 = S1 + N;
    float*          out = (float*)d_out;

    zero_kernel<<<(2 * N + 255) / 256, 256, 0, stream>>>(S1, 2 * N);
    norm_kernel<<<N / 4, 256, 0, stream>>>(X, E);

    const int NSPLIT = 8;
    dim3 grid(N / 64, NSPLIT);
    main_kernel<<<grid, 256, 0, stream>>>(E, labels, S1, S2, N, N / NSPLIT);

    finish_kernel<<<1, 1024, 0, stream>>>(S1, S2, labels, out, N);
}

// Round 2
// 121.325 us; speedup vs baseline: 1.5126x; 1.5126x over previous
//
#include <hip/hip_runtime.h>
#include <hip/hip_bf16.h>

typedef float f32x4 __attribute__((ext_vector_type(4)));
typedef __bf16 bf16x8 __attribute__((ext_vector_type(8)));

#define D_DIM 128
#define NSPLIT 32
#define SCALE  1.2011224087864498f   // sqrt(log2(e)) : both operands scaled -> acc = log2e * sim
#define LN2    0.6931471805599453f
#define E1     2.7182818284590452f

// fp32 -> bf16 round-to-nearest-even
static __device__ __forceinline__ unsigned short f2bf(float f) {
    unsigned u = __float_as_uint(f);
    u += 0x7fffu + ((u >> 16) & 1u);
    return (unsigned short)(u >> 16);
}

static __device__ __forceinline__ void gload_lds16(const unsigned short* gsrc, unsigned short* lds_dst) {
    auto gp = (const __attribute__((address_space(1))) unsigned int*)gsrc;
    auto lp = (__attribute__((address_space(3))) unsigned int*)(unsigned int)(unsigned long long)lds_dst;
    __builtin_amdgcn_global_load_lds(gp, lp, 16, 0, 0);
}

// ---------------------------------------------------------------------------
// prep: L2-normalize rows, scale by sqrt(log2e), store bf16 A; accumulate
// per-class column sums C[2][128] (fp32, of the scaled values) and count n0.
// Block: 256 thr = 4 waves; wave w handles rows blk*64 + w*16 + t.
__global__ __launch_bounds__(256) void prep_kernel(const float* __restrict__ X,
                                                   const int* __restrict__ labels,
                                                   unsigned short* __restrict__ A,
                                                   float* __restrict__ C,
                                                   int* __restrict__ n0) {
    __shared__ float CL[256];
    int tid = threadIdx.x, wave = tid >> 6, lane = tid & 63;
    CL[tid] = 0.0f;
    __syncthreads();

    int row0 = blockIdx.x * 64 + wave * 16;
    float c0x = 0.f, c0y = 0.f, c1x = 0.f, c1y = 0.f;
    int cnt0 = 0;
    for (int t = 0; t < 16; ++t) {
        int row = row0 + t;
        float2 v = *reinterpret_cast<const float2*>(X + (size_t)row * D_DIM + lane * 2);
        float ss = v.x * v.x + v.y * v.y;
        #pragma unroll
        for (int m = 32; m; m >>= 1) ss += __shfl_xor(ss, m);
        float rn = rsqrtf(ss) * SCALE;
        float a0 = v.x * rn, a1 = v.y * rn;
        ushort2 o; o.x = f2bf(a0); o.y = f2bf(a1);
        *reinterpret_cast<ushort2*>(A + (size_t)row * D_DIM + lane * 2) = o;
        bool is0 = (labels[row] == 0);
        c0x += is0 ? a0 : 0.f;  c0y += is0 ? a1 : 0.f;
        c1x += is0 ? 0.f : a0;  c1y += is0 ? 0.f : a1;
        if (lane == 0) cnt0 += is0 ? 1 : 0;
    }
    atomicAdd(&CL[lane * 2],           c0x);
    atomicAdd(&CL[lane * 2 + 1],       c0y);
    atomicAdd(&CL[128 + lane * 2],     c1x);
    atomicAdd(&CL[128 + lane * 2 + 1], c1y);
    if (lane == 0) atomicAdd(n0, cnt0);
    __syncthreads();
    atomicAdd(&C[tid], CL[tid]);
}

// ---------------------------------------------------------------------------
// main: S1part[split][i] = sum_{j in split} exp(sim_ij)
// Block: 4 waves x 64 rows = 256 rows; jlen = N/NSPLIT cols in 64-col LDS tiles.
// LDS tile layout: [col][k] bf16, XOR-swizzled: byte ^= ((col&7)<<4), staged via
// pre-swizzled global source so global_load_lds dest stays linear.
__global__ __launch_bounds__(256, 3) void main_kernel(const unsigned short* __restrict__ A,
                                                      float* __restrict__ S1part,
                                                      int N) {
    __shared__ unsigned short Bs[8192];   // 16 KB: 64 cols x 128 k
    int tid = threadIdx.x, wave = tid >> 6, lane = tid & 63;
    int l15 = lane & 15, lhi = lane >> 4;
    int m0 = blockIdx.x * 256 + wave * 64;
    int split = blockIdx.y;
    int j0 = split * (N / NSPLIT);
    const int TILES = (N / NSPLIT) / 64;

    // A fragments: rows m0 + ms*16 + l15, k = kb*32 + lhi*8 .. +7
    bf16x8 af[4][4];
    const unsigned short* abase = A + (size_t)(m0 + l15) * D_DIM + lhi * 8;
    #pragma unroll
    for (int ms = 0; ms < 4; ++ms)
        #pragma unroll
        for (int kb = 0; kb < 4; ++kb)
            af[ms][kb] = *reinterpret_cast<const bf16x8*>(abase + (size_t)ms * 16 * D_DIM + kb * 32);

    float s1[4][4];
    #pragma unroll
    for (int ms = 0; ms < 4; ++ms)
        #pragma unroll
        for (int r = 0; r < 4; ++r) s1[ms][r] = 0.0f;

    int sw = (l15 & 7) << 4;
    const char* BsB = (const char*)Bs;

    for (int t = 0; t < TILES; ++t) {
        int jt = j0 + t * 64;
        // stage 64 cols x 256 B (swizzled source -> linear LDS dest)
        #pragma unroll
        for (int it = 0; it < 4; ++it) {
            int Lb  = it * 4096 + tid * 16;
            int col = Lb >> 8;
            int off = (Lb & 255) ^ ((col & 7) << 4);
            const unsigned short* g = A + (size_t)(jt + col) * D_DIM + (off >> 1);
            gload_lds16(g, (unsigned short*)((char*)Bs + it * 4096 + wave * 1024));
        }
        __syncthreads();   // compiler drains vmcnt before s_barrier

        #pragma unroll
        for (int cs = 0; cs < 4; ++cs) {
            int colb = (cs * 16 + l15) * 256;
            bf16x8 bf[4];
            #pragma unroll
            for (int kb = 0; kb < 4; ++kb)
                bf[kb] = *reinterpret_cast<const bf16x8*>(BsB + colb + ((kb * 64 + lhi * 16) ^ sw));
            f32x4 acc[4] = {{0,0,0,0},{0,0,0,0},{0,0,0,0},{0,0,0,0}};
            #pragma unroll
            for (int kb = 0; kb < 4; ++kb)
                #pragma unroll
                for (int ms = 0; ms < 4; ++ms)
                    acc[ms] = __builtin_amdgcn_mfma_f32_16x16x32_bf16(af[ms][kb], bf[kb], acc[ms], 0, 0, 0);
            #pragma unroll
            for (int ms = 0; ms < 4; ++ms)
                #pragma unroll
                for (int r = 0; r < 4; ++r)
                    s1[ms][r] += __builtin_amdgcn_exp2f(acc[ms][r]);
        }
        __syncthreads();   // done reading before next stage overwrites
    }

    // reduce over the 16 l15 lanes holding the same rows
    #pragma unroll
    for (int m = 1; m < 16; m <<= 1)
        #pragma unroll
        for (int ms = 0; ms < 4; ++ms)
            #pragma unroll
            for (int r = 0; r < 4; ++r)
                s1[ms][r] += __shfl_xor(s1[ms][r], m);
    if (l15 == 0) {
        #pragma unroll
        for (int ms = 0; ms < 4; ++ms)
            #pragma unroll
            for (int r = 0; r < 4; ++r)
                S1part[(size_t)split * N + m0 + ms * 16 + lhi * 4 + r] = s1[ms][r];
    }
}

// ---------------------------------------------------------------------------
// finish: per row, S1 = sum of partials; denom = S1 - e; s2 = dot(a_i, C_lab)*ln2.
// Block sums -> 4 global atomics; last block combines and writes the loss.
__global__ __launch_bounds__(256) void finish_kernel(const unsigned short* __restrict__ A,
                                                     const float* __restrict__ S1part,
                                                     const float* __restrict__ C,
                                                     const int* __restrict__ labels,
                                                     int* __restrict__ n0p,
                                                     float* __restrict__ scal,
                                                     int* __restrict__ counter,
                                                     float* __restrict__ out,
                                                     int N) {
    int tid = threadIdx.x;
    int row = blockIdx.x * 256 + tid;

    float S1 = 0.0f;
    for (int s = 0; s < NSPLIT; ++s) S1 += S1part[(size_t)s * N + row];
    int lab = labels[row];
    const float* Cl = C + (lab ? 128 : 0);
    float dot = 0.0f;
    #pragma unroll
    for (int kb = 0; kb < 16; ++kb) {
        bf16x8 a = *reinterpret_cast<const bf16x8*>(A + (size_t)row * D_DIM + kb * 8);
        #pragma unroll
        for (int e = 0; e < 8; ++e) dot += (float)a[e] * Cl[kb * 8 + e];
    }
    float s2 = dot * LN2;                                  // undo the sqrt(log2e)^2 scale
    float lg = __builtin_amdgcn_logf(S1 - E1) * LN2;       // natural log of denom
    float p  = s2 - 1.0f;                                  // sum_pos sim (diag removed)
    bool is0 = (lab == 0);
    float v[4] = { is0 ? lg : 0.0f, is0 ? 0.0f : lg, is0 ? p : 0.0f, is0 ? 0.0f : p };
    #pragma unroll
    for (int m = 32; m; m >>= 1)
        #pragma unroll
        for (int q = 0; q < 4; ++q) v[q] += __shfl_xor(v[q], m);

    __shared__ float red[4][4];
    int wave = tid >> 6, lane = tid & 63;
    if (lane == 0)
        #pragma unroll
        for (int q = 0; q < 4; ++q) red[wave][q] = v[q];
    __syncthreads();
    if (tid == 0) {
        float tt[4];
        #pragma unroll
        for (int q = 0; q < 4; ++q) tt[q] = red[0][q] + red[1][q] + red[2][q] + red[3][q];
        atomicAdd(&scal[0], tt[0]);
        atomicAdd(&scal[1], tt[1]);
        atomicAdd(&scal[2], tt[2]);
        atomicAdd(&scal[3], tt[3]);
        __threadfence();
        int old = atomicAdd(counter, 1);
        if (old == (int)gridDim.x - 1) {
            float L0 = atomicAdd(&scal[0], 0.0f);
            float L1 = atomicAdd(&scal[1], 0.0f);
            float P0 = atomicAdd(&scal[2], 0.0f);
            float P1 = atomicAdd(&scal[3], 0.0f);
            int n0 = atomicAdd(n0p, 0);
            float fn0 = (float)n0, fn1 = (float)(N - n0);
            float loss = ((fn0 - 1.0f) * L0 - P0) / fn0 + (fn1 - 1.0f) * L1 - P1;
            out[0] = loss;
        }
    }
}

// ---------------------------------------------------------------------------
extern "C" void kernel_launch(void* const* d_in, const int* in_sizes, int n_in,
                              void* d_out, int out_size, void* d_ws, size_t ws_size,
                              hipStream_t stream) {
    (void)n_in; (void)out_size; (void)ws_size;
    const float* X      = (const float*)d_in[0];
    const int*   labels = (const int*)d_in[1];
    int N = in_sizes[1];                       // 8192; assumes D=128, N % 256 == 0

    char* ws = (char*)d_ws;
    size_t A_bytes  = (size_t)N * D_DIM * 2;           // 2 MB
    size_t S1_bytes = (size_t)NSPLIT * N * 4;          // 1 MB
    unsigned short* A      = (unsigned short*)ws;
    float*          S1part = (float*)(ws + A_bytes);
    float*          C      = (float*)(ws + A_bytes + S1_bytes);
    float*          scal   = (float*)((char*)C + 1024);
    int*            n0     = (int*)((char*)scal + 16);
    int*            counter= (int*)((char*)n0 + 4);
    float*          out    = (float*)d_out;

    hipMemsetAsync(C, 0, 1024 + 16 + 4 + 4, stream);

    prep_kernel<<<N / 64, 256, 0, stream>>>(X, labels, A, C, n0);

    dim3 grid(N / 256, NSPLIT);
    main_kernel<<<grid, 256, 0, stream>>>(A, S1part, N);

    finish_kernel<<<N / 256, 256, 0, stream>>>(A, S1part, C, labels, n0, scal, counter, out, N);
}